// Round 9
// baseline (349.471 us; speedup 1.0000x reference)
//
#include <hip/hip_runtime.h>

typedef _Float16 half8 __attribute__((ext_vector_type(8)));
typedef _Float16 half2v __attribute__((ext_vector_type(2)));
typedef float f32x4 __attribute__((ext_vector_type(4)));

#define S_LEN 4096
#define D_DIM 4096
#define HD 128

// ws layout: qw [8192][128] f16 @0; kw @2MiB; vt [2][128][4096] f16 @4MiB;
// wh (f16 weights) @6MiB (3MiB); P (K-split partials f32) @9MiB (24MiB);
// tab (cos/sin table [4096][64] float2) @33MiB (2MiB).

__device__ __forceinline__ void gload_lds16(const _Float16* g, _Float16* l) {
    __builtin_amdgcn_global_load_lds(
        (const __attribute__((address_space(1))) unsigned int*)g,
        (__attribute__((address_space(3))) unsigned int*)l, 16, 0, 0);
}

// ---------------- kernel 0: W f32 -> f16 ----------------
__global__ __launch_bounds__(256) void convw_kernel(const float* __restrict__ wq,
                                                    const float* __restrict__ wk,
                                                    const float* __restrict__ wv,
                                                    _Float16* __restrict__ wh) {
    const int g = blockIdx.x * 256 + threadIdx.x;  // 196608
    const int p = g >> 16;
    const int off = (g & 65535) * 8;
    const float* src = ((p == 0) ? wq : (p == 1) ? wk : wv) + off;
    float4 v0 = *(const float4*)src;
    float4 v1 = *(const float4*)(src + 4);
    half8 h = { (_Float16)v0.x, (_Float16)v0.y, (_Float16)v0.z, (_Float16)v0.w,
                (_Float16)v1.x, (_Float16)v1.y, (_Float16)v1.z, (_Float16)v1.w };
    *(half8*)&wh[(size_t)p * 524288 + off] = h;
}

// ---------------- kernel 0c: RoPE cos/sin table (slow-path sincos done ONCE) ----------------
__global__ __launch_bounds__(256) void trig_kernel(float* __restrict__ tab) {
    const int g = blockIdx.x * 256 + threadIdx.x;  // 262144 = 4096 x 64
    const int s = g >> 6, p = g & 63;
    const float theta = exp2f((float)p * -0.4152410118609203f);  // 10000^(-p/32)
    float sn, cn;
    sincosf((float)s * theta, &sn, &cn);
    *(float2*)&tab[g * 2] = (float2){cn, sn};
}

// ---------------- kernel 1: QKV GEMM, BK=64 phases (R16) ----------------
// R16: 32 phases of BK=64 instead of 64 of BK=32 -- each __syncthreads() drain
// (vmcnt(0), the m97 structural stall: every barrier waits on ALL in-flight loads,
// including the 1-phase-old B-DMA and A-prefetch) is amortized over 2x the MFMA work.
// Fragment-major LDS (R10/R12-verified), A reg-staged (x is f32), B global_load_lds.
// LDS: per buffer A 8 frags + B 16 frags x 512 f16 = 24KB; 2 buffers = 48KB -> 3 blocks/CU.
__global__ __launch_bounds__(256, 3) void proj64_kernel(const float* __restrict__ x,
                                                        const _Float16* __restrict__ wh,
                                                        float* __restrict__ P) {
    __shared__ __align__(16) _Float16 smem[24576];  // 2 x 12288 | f32 epilogue union
    const int tid = threadIdx.x;
    const int wg = blockIdx.x;
    const int swz = (wg & 7) * 96 + (wg >> 3);  // bijective XCD chunking (768 blocks)
    const int bx = swz % 3;
    const int rest = swz / 3;
    const int ks = rest & 1;
    const int M0 = (rest >> 1) * 64;
    const int lane = tid & 63, wv_ = tid >> 6;
    const int l15 = lane & 15, quad = lane >> 4;

    // A staging: 64 rows x 64 cols f32 per phase; thread owns (arow, 16 cols)
    const int arow = tid >> 2, acol = (tid & 3) * 16;
    const float* xa = x + (size_t)(M0 + arow) * D_DIM + acol + ks * (D_DIM / 2);
    // A frag-major chunk offsets: frag(mi,kk) lane l -> ((mi*2+kk)*64 + l)*8 f16.
    // writer chunk (row, col8): mi=row>>4, kk=col8>>2, lane=(row&15)+(col8&3)*16
    const int c8a = (tid & 3) * 2;
    const int awoff0 = (((arow >> 4) * 2 + (c8a >> 2)) * 64 + (arow & 15) + (c8a & 3) * 16) * 8;
    const int c8b = c8a + 1;
    const int awoff1 = (((arow >> 4) * 2 + (c8b >> 2)) * 64 + (arow & 15) + (c8b & 3) * 16) * 8;

    // B DMA source: frag(wv,ni,kk) lane l <- wh[(wv*32+ni*16+(l&15))*D + kk*32+(l>>4)*8]
    const _Float16* wsrc = wh + (size_t)bx * 524288 + ks * (D_DIM / 2) +
                           (size_t)(wv_ * 32 + l15) * D_DIM + quad * 8;

    f32x4 acc[4][2];
    for (int mi = 0; mi < 4; ++mi)
        for (int ni = 0; ni < 2; ++ni)
            acc[mi][ni] = (f32x4){0.f, 0.f, 0.f, 0.f};

    auto stageA = [&](_Float16* buf, float4 A0, float4 A1, float4 A2, float4 A3) {
        half8 h0 = { (_Float16)A0.x, (_Float16)A0.y, (_Float16)A0.z, (_Float16)A0.w,
                     (_Float16)A1.x, (_Float16)A1.y, (_Float16)A1.z, (_Float16)A1.w };
        half8 h1 = { (_Float16)A2.x, (_Float16)A2.y, (_Float16)A2.z, (_Float16)A2.w,
                     (_Float16)A3.x, (_Float16)A3.y, (_Float16)A3.z, (_Float16)A3.w };
        *(half8*)&buf[awoff0] = h0;
        *(half8*)&buf[awoff1] = h1;
    };
    auto stageB = [&](_Float16* buf, int p) {
        const _Float16* s = wsrc + p * 64;
        gload_lds16(s,                     &buf[4096 + ((wv_ * 2 + 0) * 2 + 0) * 512]);
        gload_lds16(s + 32,                &buf[4096 + ((wv_ * 2 + 0) * 2 + 1) * 512]);
        gload_lds16(s + 16 * D_DIM,        &buf[4096 + ((wv_ * 2 + 1) * 2 + 0) * 512]);
        gload_lds16(s + 16 * D_DIM + 32,   &buf[4096 + ((wv_ * 2 + 1) * 2 + 1) * 512]);
    };
    auto compute = [&](const _Float16* buf) {
        const _Float16* Af = buf + lane * 8;
        const _Float16* Bf = buf + 4096 + wv_ * 2048 + lane * 8;
        half8 af[4][2], bf[2][2];
        for (int mi = 0; mi < 4; ++mi)
            for (int kk = 0; kk < 2; ++kk)
                af[mi][kk] = *(const half8*)(Af + (mi * 2 + kk) * 512);
        for (int ni = 0; ni < 2; ++ni)
            for (int kk = 0; kk < 2; ++kk)
                bf[ni][kk] = *(const half8*)(Bf + (ni * 2 + kk) * 512);
        for (int kk = 0; kk < 2; ++kk)
            for (int mi = 0; mi < 4; ++mi)
                for (int ni = 0; ni < 2; ++ni)
                    acc[mi][ni] = __builtin_amdgcn_mfma_f32_16x16x32_f16(af[mi][kk], bf[ni][kk],
                                                                         acc[mi][ni], 0, 0, 0);
    };

#define LOADA(R0, R1, R2, R3, p)                           \
    R0 = *(const float4*)(xa + (p) * 64);                  \
    R1 = *(const float4*)(xa + (p) * 64 + 4);              \
    R2 = *(const float4*)(xa + (p) * 64 + 8);              \
    R3 = *(const float4*)(xa + (p) * 64 + 12);

    float4 aA0, aA1, aA2, aA3, aB0, aB1, aB2, aB3;
    LOADA(aA0, aA1, aA2, aA3, 0)
    LOADA(aB0, aB1, aB2, aB3, 1)
    stageB(smem, 0);

    for (int p = 0; p < 32; p += 2) {
        // ---- phase p via buf0 ----
        stageA(smem, aA0, aA1, aA2, aA3);
        __syncthreads();                       // drains DMA(buf0,p) + A ds_writes
        if (p + 2 < 32) { LOADA(aA0, aA1, aA2, aA3, p + 2) }
        stageB(smem + 12288, p + 1);           // next phase's DMA in flight
        compute(smem);
        // ---- phase p+1 via buf1 ----
        stageA(smem + 12288, aB0, aB1, aB2, aB3);
        __syncthreads();                       // drains DMA(buf1,p+1)
        if (p + 3 < 32) { LOADA(aB0, aB1, aB2, aB3, p + 3) }
        if (p + 2 < 32) stageB(smem, p + 2);   // buf0 reads complete (lgkm at barrier)
        compute(smem + 12288);
    }
#undef LOADA
    __syncthreads();

    // f32 partial epilogue (R9/R12-verified): row(M)=mi*16+quad*4+r, col=wv_*32+ni*16+l15
    float* sf = (float*)smem;  // [64][132] f32 = 33792 B <= 49152 B
    for (int mi = 0; mi < 4; ++mi)
        for (int ni = 0; ni < 2; ++ni)
            for (int r = 0; r < 4; ++r)
                sf[(mi * 16 + quad * 4 + r) * 132 + wv_ * 32 + ni * 16 + l15] =
                    acc[mi][ni][r];
    __syncthreads();
    const int row = tid >> 2, c0 = (tid & 3) * 32;
    float* dst = P + ((size_t)(ks * 3 + bx) * 8192 + M0 + row) * HD + c0;
    for (int j = 0; j < 8; ++j)
        *(float4*)(dst + j * 4) = *(const float4*)&sf[row * 132 + c0 + j * 4];
}

// ---------------- kernel 1-fallback: R12 proj (KSPLIT=1 only) ----------------
#define QSTR 136
__global__ __launch_bounds__(256) void proj_kernel(const float* __restrict__ x,
                                                   const _Float16* __restrict__ wh,
                                                   _Float16* __restrict__ qw,
                                                   _Float16* __restrict__ kw,
                                                   _Float16* __restrict__ vt) {
    __shared__ __align__(16) _Float16 smem[17408];
    const int tid = threadIdx.x;
    const int wg = blockIdx.x;
    const int swz = (wg & 7) * 48 + (wg >> 3);
    const int bx = swz % 3;
    const int M0 = (swz / 3) * 64;
    const int lane = tid & 63, wv_ = tid >> 6;
    const int l15 = lane & 15, quad = lane >> 4;

    const int arow = tid >> 2, acol = (tid & 3) * 8;
    const float* xa = x + (size_t)(M0 + arow) * D_DIM + acol;
    const _Float16* wsrc = wh + (size_t)bx * 128 * D_DIM +
                           (size_t)(wv_ * 32 + l15) * D_DIM + quad * 8;
    const int awoff = ((arow >> 4) * 64 + (arow & 15) + (tid & 3) * 16) * 8;
    const int rdoff = lane * 8;

    f32x4 acc[4][2];
    for (int mi = 0; mi < 4; ++mi)
        for (int ni = 0; ni < 2; ++ni)
            acc[mi][ni] = (f32x4){0.f, 0.f, 0.f, 0.f};

    auto stageA = [&](_Float16* buf, float4 A0, float4 A1) {
        half8 ha = { (_Float16)A0.x, (_Float16)A0.y, (_Float16)A0.z, (_Float16)A0.w,
                     (_Float16)A1.x, (_Float16)A1.y, (_Float16)A1.z, (_Float16)A1.w };
        *(half8*)&buf[awoff] = ha;
    };
    auto stageB = [&](_Float16* buf, int slab) {
        const _Float16* s = wsrc + slab * 32;
        gload_lds16(s,              &buf[2048 + wv_ * 1024]);
        gload_lds16(s + 16 * D_DIM, &buf[2048 + wv_ * 1024 + 512]);
    };
    auto compute = [&](const _Float16* buf) {
        const _Float16* Af = buf + rdoff;
        const _Float16* Bf = buf + 2048 + wv_ * 1024 + rdoff;
        half8 af[4], bf[2];
        for (int mi = 0; mi < 4; ++mi)
            af[mi] = *(const half8*)(Af + mi * 512);
        for (int ni = 0; ni < 2; ++ni)
            bf[ni] = *(const half8*)(Bf + ni * 512);
        for (int mi = 0; mi < 4; ++mi)
            for (int ni = 0; ni < 2; ++ni)
                acc[mi][ni] = __builtin_amdgcn_mfma_f32_16x16x32_f16(af[mi], bf[ni],
                                                                     acc[mi][ni], 0, 0, 0);
    };

    float4 a0_0, a0_1, a1_0, a1_1;
    a0_0 = *(const float4*)(xa);      a0_1 = *(const float4*)(xa + 4);
    a1_0 = *(const float4*)(xa + 32); a1_1 = *(const float4*)(xa + 36);
    stageB(smem, 0);

    for (int i = 0; i < 128; i += 2) {
        stageA(smem, a0_0, a0_1);
        __syncthreads();
        if (i + 2 < 128) {
            a0_0 = *(const float4*)(xa + (i + 2) * 32);
            a0_1 = *(const float4*)(xa + (i + 2) * 32 + 4);
        }
        stageB(smem + 6144, i + 1);
        compute(smem);
        stageA(smem + 6144, a1_0, a1_1);
        __syncthreads();
        if (i + 3 < 128) {
            a1_0 = *(const float4*)(xa + (i + 3) * 32);
            a1_1 = *(const float4*)(xa + (i + 3) * 32 + 4);
        }
        if (i + 2 < 128) stageB(smem, i + 2);
        compute(smem + 6144);
    }
    __syncthreads();

    if (bx < 2) {
        for (int mi = 0; mi < 4; ++mi)
            for (int ni = 0; ni < 2; ++ni)
                for (int r = 0; r < 4; ++r)
                    smem[(mi * 16 + quad * 4 + r) * QSTR + wv_ * 32 + ni * 16 + l15] =
                        (_Float16)acc[mi][ni][r];
        __syncthreads();
        _Float16* dst = ((bx == 0) ? qw : kw) + (size_t)M0 * HD;
        const int row = tid >> 2, c0 = (tid & 3) * 32;
        for (int j = 0; j < 4; ++j)
            *(half8*)&dst[row * HD + c0 + j * 8] = *(const half8*)&smem[row * QSTR + c0 + j * 8];
    } else {
        for (int mi = 0; mi < 4; ++mi)
            for (int ni = 0; ni < 2; ++ni)
                for (int r = 0; r < 4; ++r)
                    smem[(wv_ * 32 + ni * 16 + l15) * QSTR + mi * 16 + quad * 4 + r] =
                        (_Float16)acc[mi][ni][r];
        __syncthreads();
        _Float16* dst = vt + (size_t)(M0 >> 12) * HD * S_LEN + (M0 & (S_LEN - 1));
        const int hd = tid >> 1, s0 = (tid & 1) * 32;
        for (int j = 0; j < 4; ++j)
            *(half8*)&dst[(size_t)hd * S_LEN + s0 + j * 8] =
                *(const half8*)&smem[hd * QSTR + s0 + j * 8];
    }
}

// ---------------- kernel 1b: combine K-split partials + RoPE (table) + V-transpose ----------------
__global__ __launch_bounds__(256) void combine_kernel(const float* __restrict__ P,
                                                      const float* __restrict__ tab,
                                                      _Float16* __restrict__ qw,
                                                      _Float16* __restrict__ kw,
                                                      _Float16* __restrict__ vt) {
    const int tid = threadIdx.x;
    const int M0 = blockIdx.x * 64;
    const int row = tid >> 2, c0 = (tid & 3) * 32;
    if (blockIdx.y == 0) {
        const float* Pq0 = P + ((size_t)0 * 8192 + M0 + row) * HD + c0;
        const float* Pq1 = P + ((size_t)3 * 8192 + M0 + row) * HD + c0;
        const float* Pk0 = P + ((size_t)1 * 8192 + M0 + row) * HD + c0;
        const float* Pk1 = P + ((size_t)4 * 8192 + M0 + row) * HD + c0;
        float qv[32], kv[32];
#pragma unroll
        for (int j = 0; j < 8; ++j) {
            float4 a = *(const float4*)(Pq0 + j * 4);
            float4 b = *(const float4*)(Pq1 + j * 4);
            float4 c = *(const float4*)(Pk0 + j * 4);
            float4 d = *(const float4*)(Pk1 + j * 4);
            qv[j * 4 + 0] = a.x + b.x; qv[j * 4 + 1] = a.y + b.y;
            qv[j * 4 + 2] = a.z + b.z; qv[j * 4 + 3] = a.w + b.w;
            kv[j * 4 + 0] = c.x + d.x; kv[j * 4 + 1] = c.y + d.y;
            kv[j * 4 + 2] = c.z + d.z; kv[j * 4 + 3] = c.w + d.w;
        }
        const int s = (M0 + row) & (S_LEN - 1);
        const float2* tb = (const float2*)tab + s * 64 + (c0 >> 1);
        half8 oq[4], ok[4];
#pragma unroll
        for (int jp = 0; jp < 16; ++jp) {
            const float2 cs = tb[jp];
            const float cn = cs.x, sn = cs.y;
            const float q0 = qv[2 * jp], q1 = qv[2 * jp + 1];
            const float k0 = kv[2 * jp], k1 = kv[2 * jp + 1];
            oq[jp >> 2][(2 * jp) & 7]     = (_Float16)(q0 * cn - q1 * sn);
            oq[jp >> 2][(2 * jp + 1) & 7] = (_Float16)(q1 * cn + q0 * sn);
            ok[jp >> 2][(2 * jp) & 7]     = (_Float16)(k0 * cn - k1 * sn);
            ok[jp >> 2][(2 * jp + 1) & 7] = (_Float16)(k1 * cn + k0 * sn);
        }
        _Float16* qdst = qw + (size_t)(M0 + row) * HD + c0;
        _Float16* kdst = kw + (size_t)(M0 + row) * HD + c0;
#pragma unroll
        for (int j = 0; j < 4; ++j) {
            *(half8*)(qdst + j * 8) = oq[j];
            *(half8*)(kdst + j * 8) = ok[j];
        }
    } else {
        __shared__ __align__(16) _Float16 sh[128][72];
        const float* Pv0 = P + ((size_t)2 * 8192 + M0 + row) * HD + c0;
        const float* Pv1 = P + ((size_t)5 * 8192 + M0 + row) * HD + c0;
#pragma unroll
        for (int j = 0; j < 8; ++j) {
            float4 a = *(const float4*)(Pv0 + j * 4);
            float4 b = *(const float4*)(Pv1 + j * 4);
            sh[c0 + j * 4 + 0][row] = (_Float16)(a.x + b.x);
            sh[c0 + j * 4 + 1][row] = (_Float16)(a.y + b.y);
            sh[c0 + j * 4 + 2][row] = (_Float16)(a.z + b.z);
            sh[c0 + j * 4 + 3][row] = (_Float16)(a.w + b.w);
        }
        __syncthreads();
        const int hd = tid >> 1, s0 = (tid & 1) * 32;
        _Float16* dst = vt + (size_t)(M0 >> 12) * HD * S_LEN + (size_t)hd * S_LEN +
                        (M0 & (S_LEN - 1)) + s0;
        for (int j = 0; j < 4; ++j)
            *(half8*)(dst + j * 8) = *(const half8*)&sh[hd][s0 + j * 8];
    }
}

// ---------------- kernel 2 (fallback only): RoPE on q,k in place ----------------
__global__ __launch_bounds__(256) void rope_kernel(_Float16* __restrict__ qw,
                                                   _Float16* __restrict__ kw) {
    const int g = blockIdx.x * 256 + threadIdx.x;
    const int m = g >> 6, p = g & 63;
    const int s = m & (S_LEN - 1);
    const float theta = exp2f((float)p * -0.4152410118609203f);
    float sn, cn;
    sincosf((float)s * theta, &sn, &cn);
    const size_t off = (size_t)m * HD + 2 * p;
    half2v qv = *(half2v*)&qw[off];
    half2v kv = *(half2v*)&kw[off];
    float q0 = qv[0], q1 = qv[1], k0 = kv[0], k1 = kv[1];
    half2v qo = { (_Float16)(q0 * cn - q1 * sn), (_Float16)(q1 * cn + q0 * sn) };
    half2v ko = { (_Float16)(k0 * cn - k1 * sn), (_Float16)(k1 * cn + k0 * sn) };
    *(half2v*)&qw[off] = qo;
    *(half2v*)&kw[off] = ko;
}

// ---------------- kernel 3: attention (R3-verified monolithic) ----------------
__device__ __forceinline__ void load_kf(const _Float16* __restrict__ kb, int kbase,
                                        int l15, int quad, half8* kf) {
    const _Float16* kr = kb + (size_t)(kbase + l15) * HD + quad * 8;
    for (int kk = 0; kk < 4; ++kk) {
        kf[kk]     = *(const half8*)(kr + kk * 32);
        kf[4 + kk] = *(const half8*)(kr + 16 * HD + kk * 32);
    }
}

template<bool MASKED>
__device__ __forceinline__ void attn_tile(int kbase, int qg, int l15, int quad,
                                          const half8* kf,
                                          const _Float16* __restrict__ vtb,
                                          const half8* bq, f32x4* acc,
                                          float& mrun, float& lrun) {
    const float csc = 0.1275174348796053f;  // (1/sqrt(128)) * log2(e)
    half8 va[8];
    const _Float16* vr = vtb + (size_t)l15 * S_LEN + kbase + quad * 8;
    for (int c = 0; c < 8; ++c)
        va[c] = *(const half8*)(vr + (size_t)c * 16 * S_LEN);
    f32x4 st0 = (f32x4){0.f, 0.f, 0.f, 0.f};
    f32x4 st1 = (f32x4){0.f, 0.f, 0.f, 0.f};
    for (int kk = 0; kk < 4; ++kk) {
        st0 = __builtin_amdgcn_mfma_f32_16x16x32_f16(kf[kk],     bq[kk], st0, 0, 0, 0);
        st1 = __builtin_amdgcn_mfma_f32_16x16x32_f16(kf[4 + kk], bq[kk], st1, 0, 0, 0);
    }
    float p0[4], p1[4];
    float mloc = -1e30f;
    for (int r = 0; r < 4; ++r) {
        float v0 = st0[r] * csc;
        float v1 = st1[r] * csc;
        if (MASKED) {
            const int key0 = kbase + quad * 4 + r;
            if (key0 > qg)      v0 = -1e30f;
            if (key0 + 16 > qg) v1 = -1e30f;
        }
        p0[r] = v0; p1[r] = v1;
        mloc = fmaxf(mloc, fmaxf(v0, v1));
    }
    mloc = fmaxf(mloc, __shfl_xor(mloc, 16));
    mloc = fmaxf(mloc, __shfl_xor(mloc, 32));
    const float mnew = fmaxf(mrun, mloc);
    const float alpha = exp2f(mrun - mnew);
    mrun = mnew;
    float ls = 0.f;
    for (int r = 0; r < 4; ++r) {
        p0[r] = exp2f(p0[r] - mnew);
        p1[r] = exp2f(p1[r] - mnew);
        ls += p0[r] + p1[r];
    }
    ls += __shfl_xor(ls, 16);
    ls += __shfl_xor(ls, 32);
    lrun = lrun * alpha + ls;
    for (int c = 0; c < 8; ++c)
        acc[c] *= alpha;
    int ph0 = __builtin_bit_cast(int, __builtin_amdgcn_cvt_pkrtz(p0[0], p0[1]));
    int ph1 = __builtin_bit_cast(int, __builtin_amdgcn_cvt_pkrtz(p0[2], p0[3]));
    int ph2 = __builtin_bit_cast(int, __builtin_amdgcn_cvt_pkrtz(p1[0], p1[1]));
    int ph3 = __builtin_bit_cast(int, __builtin_amdgcn_cvt_pkrtz(p1[2], p1[3]));
    const int s0 = (l15 + (((quad << 1)    ) & 3) * 16) * 4;
    const int s1 = (l15 + (((quad << 1) + 1) & 3) * 16) * 4;
    int a0 = __builtin_amdgcn_ds_bpermute(s0, ph0);
    int a1 = __builtin_amdgcn_ds_bpermute(s0, ph1);
    int a2 = __builtin_amdgcn_ds_bpermute(s1, ph0);
    int a3 = __builtin_amdgcn_ds_bpermute(s1, ph1);
    int b0 = __builtin_amdgcn_ds_bpermute(s0, ph2);
    int b1 = __builtin_amdgcn_ds_bpermute(s0, ph3);
    int b2 = __builtin_amdgcn_ds_bpermute(s1, ph2);
    int b3 = __builtin_amdgcn_ds_bpermute(s1, ph3);
    const bool lo = quad < 2;
    int4 pi = { lo ? a0 : b0, lo ? a1 : b1, lo ? a2 : b2, lo ? a3 : b3 };
    half8 pf = __builtin_bit_cast(half8, pi);
    for (int c = 0; c < 8; ++c)
        acc[c] = __builtin_amdgcn_mfma_f32_16x16x32_f16(va[c], pf, acc[c], 0, 0, 0);
}

__global__ __launch_bounds__(256) void attn_kernel(const _Float16* __restrict__ q,
                                                   const _Float16* __restrict__ k,
                                                   const _Float16* __restrict__ vt,
                                                   float* __restrict__ out) {
    __shared__ __align__(16) float Osh[4][16][132];
    __shared__ float msh[4][16];
    __shared__ float lsh[4][16];
    const int tid = threadIdx.x;
    const int lane = tid & 63, wv_ = tid >> 6;
    const int l15 = lane & 15, quad = lane >> 4;
    const int bidx = blockIdx.x;
    const int b = bidx & 1;
    const int t = 255 - (bidx >> 1);
    const int qb = t * 16;
    const int qg = qb + l15;

    const _Float16* qp = q + (size_t)(b * S_LEN + qb) * HD;
    half8 bq[4];
    for (int kk = 0; kk < 4; ++kk)
        bq[kk] = *(const half8*)&qp[l15 * HD + kk * 32 + quad * 8];

    f32x4 acc[8];
    for (int c = 0; c < 8; ++c) acc[c] = (f32x4){0.f, 0.f, 0.f, 0.f};
    float mrun = -1e30f, lrun = 0.f;

    const _Float16* kb = k + (size_t)b * S_LEN * HD;
    const _Float16* vtb = vt + (size_t)b * HD * S_LEN;

    const int nfull = (qb + 1) >> 5;
    const int kend = nfull * 32;
    const bool hasm = ((nfull & 3) == wv_);
    const int kb0 = wv_ * 32;

    half8 kf[8], kf2[8];
    if (kb0 < kend)      load_kf(kb, kb0, l15, quad, kf);
    else if (hasm)       load_kf(kb, kend, l15, quad, kf);
    for (int kbase = kb0; kbase < kend; kbase += 128) {
        const int kn = kbase + 128;
        if (kn < kend)   load_kf(kb, kn, l15, quad, kf2);
        else if (hasm)   load_kf(kb, kend, l15, quad, kf2);
        attn_tile<false>(kbase, qg, l15, quad, kf, vtb, bq, acc, mrun, lrun);
        for (int j = 0; j < 8; ++j) kf[j] = kf2[j];
    }
    if (hasm)
        attn_tile<true>(kend, qg, l15, quad, kf, vtb, bq, acc, mrun, lrun);

    for (int c = 0; c < 8; ++c)
        *(f32x4*)&Osh[wv_][l15][c * 16 + quad * 4] = acc[c];
    if (quad == 0) { msh[wv_][l15] = mrun; lsh[wv_][l15] = lrun; }
    __syncthreads();

    const int qr = tid >> 4, dg = (tid & 15) * 8;
    float m0 = msh[0][qr], m1 = msh[1][qr], m2 = msh[2][qr], m3 = msh[3][qr];
    float mm = fmaxf(fmaxf(m0, m1), fmaxf(m2, m3));
    float f0 = exp2f(m0 - mm), f1 = exp2f(m1 - mm), f2 = exp2f(m2 - mm), f3 = exp2f(m3 - mm);
    float l = lsh[0][qr] * f0 + lsh[1][qr] * f1 + lsh[2][qr] * f2 + lsh[3][qr] * f3;
    f32x4 oa = (f32x4){0.f, 0.f, 0.f, 0.f}, ob = oa;
    oa += *(f32x4*)&Osh[0][qr][dg] * f0;  ob += *(f32x4*)&Osh[0][qr][dg + 4] * f0;
    oa += *(f32x4*)&Osh[1][qr][dg] * f1;  ob += *(f32x4*)&Osh[1][qr][dg + 4] * f1;
    oa += *(f32x4*)&Osh[2][qr][dg] * f2;  ob += *(f32x4*)&Osh[2][qr][dg + 4] * f2;
    oa += *(f32x4*)&Osh[3][qr][dg] * f3;  ob += *(f32x4*)&Osh[3][qr][dg + 4] * f3;
    const float inv = 1.0f / l;
    float* op = out + (size_t)(b * S_LEN + qb + qr) * HD + dg;
    *(float4*)op       = (float4){oa[0] * inv, oa[1] * inv, oa[2] * inv, oa[3] * inv};
    *(float4*)(op + 4) = (float4){ob[0] * inv, ob[1] * inv, ob[2] * inv, ob[3] * inv};
}

extern "C" void kernel_launch(void* const* d_in, const int* in_sizes, int n_in,
                              void* d_out, int out_size, void* d_ws, size_t ws_size,
                              hipStream_t stream) {
    const float* x  = (const float*)d_in[0];
    const float* Wq = (const float*)d_in[1];
    const float* Wk = (const float*)d_in[2];
    const float* Wv = (const float*)d_in[3];
    float* out = (float*)d_out;
    char* ws = (char*)d_ws;
    _Float16* qw = (_Float16*)(ws);
    _Float16* kw = (_Float16*)(ws + (2u << 20));
    _Float16* vt = (_Float16*)(ws + (4u << 20));
    _Float16* wh = (_Float16*)(ws + (6u << 20));            // 3 MiB
    float* P   = (float*)(ws + (9u << 20));                 // 24 MiB
    float* tab = (float*)(ws + (33u << 20));                // 2 MiB

    const size_t need = (size_t)(35u << 20);
    convw_kernel<<<dim3(768), dim3(256), 0, stream>>>(Wq, Wk, Wv, wh);
    if (ws_size >= need) {
        trig_kernel<<<dim3(1024), dim3(256), 0, stream>>>(tab);
        proj64_kernel<<<dim3(768), dim3(256), 0, stream>>>(x, wh, P);
        combine_kernel<<<dim3(128, 2), dim3(256), 0, stream>>>(P, tab, qw, kw, vt);
    } else {
        proj_kernel<<<dim3(384), dim3(256), 0, stream>>>(x, wh, qw, kw, vt);
        rope_kernel<<<dim3(2048), dim3(256), 0, stream>>>(qw, kw);
    }
    attn_kernel<<<dim3(512), dim3(256), 0, stream>>>(qw, kw, vt, out);
}

// Round 10
// 322.565 us; speedup vs baseline: 1.0834x; 1.0834x over previous
//
#include <hip/hip_runtime.h>

typedef _Float16 half8 __attribute__((ext_vector_type(8)));
typedef _Float16 half2v __attribute__((ext_vector_type(2)));
typedef float f32x4 __attribute__((ext_vector_type(4)));

#define S_LEN 4096
#define D_DIM 4096
#define HD 128

// ws layout: qw [8192][128] f16 @0; kw @2MiB; vt [2][128][4096] f16 @4MiB;
// wh (f16 weights) @6MiB (3MiB); P (K-split partials f32) @9MiB (24MiB);
// tab (cos/sin table [4096][64] float2) @33MiB (2MiB).

__device__ __forceinline__ void gload_lds16(const _Float16* g, _Float16* l) {
    __builtin_amdgcn_global_load_lds(
        (const __attribute__((address_space(1))) unsigned int*)g,
        (__attribute__((address_space(3))) unsigned int*)l, 16, 0, 0);
}

// ---------------- kernel 0: setup = W f32->f16 + RoPE trig table (fused) ----------------
__global__ __launch_bounds__(256) void setup_kernel(const float* __restrict__ wq,
                                                    const float* __restrict__ wk,
                                                    const float* __restrict__ wv,
                                                    _Float16* __restrict__ wh,
                                                    float* __restrict__ tab) {
    const int g = blockIdx.x * 256 + threadIdx.x;  // 196608 W-chunks + 262144 trig
    if (g < 196608) {
        const int p = g >> 16;
        const int off = (g & 65535) * 8;
        const float* src = ((p == 0) ? wq : (p == 1) ? wk : wv) + off;
        float4 v0 = *(const float4*)src;
        float4 v1 = *(const float4*)(src + 4);
        half8 h = { (_Float16)v0.x, (_Float16)v0.y, (_Float16)v0.z, (_Float16)v0.w,
                    (_Float16)v1.x, (_Float16)v1.y, (_Float16)v1.z, (_Float16)v1.w };
        *(half8*)&wh[(size_t)p * 524288 + off] = h;
    } else {
        const int h = g - 196608;   // 262144 = 4096 x 64
        const int s = h >> 6, p = h & 63;
        const float theta = exp2f((float)p * -0.4152410118609203f);  // 10000^(-p/32)
        float sn, cn;
        sincosf((float)s * theta, &sn, &cn);
        *(float2*)&tab[h * 2] = (float2){cn, sn};
    }
}

// ---------------- kernel 1: QKV GEMM, BK=64 (R16-verified) ----------------
__global__ __launch_bounds__(256, 3) void proj64_kernel(const float* __restrict__ x,
                                                        const _Float16* __restrict__ wh,
                                                        float* __restrict__ P) {
    __shared__ __align__(16) _Float16 smem[24576];  // 2 x 12288 | f32 epilogue union
    const int tid = threadIdx.x;
    const int wg = blockIdx.x;
    const int swz = (wg & 7) * 96 + (wg >> 3);  // bijective XCD chunking (768 blocks)
    const int bx = swz % 3;
    const int rest = swz / 3;
    const int ks = rest & 1;
    const int M0 = (rest >> 1) * 64;
    const int lane = tid & 63, wv_ = tid >> 6;
    const int l15 = lane & 15, quad = lane >> 4;

    const int arow = tid >> 2, acol = (tid & 3) * 16;
    const float* xa = x + (size_t)(M0 + arow) * D_DIM + acol + ks * (D_DIM / 2);
    const int c8a = (tid & 3) * 2;
    const int awoff0 = (((arow >> 4) * 2 + (c8a >> 2)) * 64 + (arow & 15) + (c8a & 3) * 16) * 8;
    const int c8b = c8a + 1;
    const int awoff1 = (((arow >> 4) * 2 + (c8b >> 2)) * 64 + (arow & 15) + (c8b & 3) * 16) * 8;

    const _Float16* wsrc = wh + (size_t)bx * 524288 + ks * (D_DIM / 2) +
                           (size_t)(wv_ * 32 + l15) * D_DIM + quad * 8;

    f32x4 acc[4][2];
    for (int mi = 0; mi < 4; ++mi)
        for (int ni = 0; ni < 2; ++ni)
            acc[mi][ni] = (f32x4){0.f, 0.f, 0.f, 0.f};

    auto stageA = [&](_Float16* buf, float4 A0, float4 A1, float4 A2, float4 A3) {
        half8 h0 = { (_Float16)A0.x, (_Float16)A0.y, (_Float16)A0.z, (_Float16)A0.w,
                     (_Float16)A1.x, (_Float16)A1.y, (_Float16)A1.z, (_Float16)A1.w };
        half8 h1 = { (_Float16)A2.x, (_Float16)A2.y, (_Float16)A2.z, (_Float16)A2.w,
                     (_Float16)A3.x, (_Float16)A3.y, (_Float16)A3.z, (_Float16)A3.w };
        *(half8*)&buf[awoff0] = h0;
        *(half8*)&buf[awoff1] = h1;
    };
    auto stageB = [&](_Float16* buf, int p) {
        const _Float16* s = wsrc + p * 64;
        gload_lds16(s,                   &buf[4096 + ((wv_ * 2 + 0) * 2 + 0) * 512]);
        gload_lds16(s + 32,              &buf[4096 + ((wv_ * 2 + 0) * 2 + 1) * 512]);
        gload_lds16(s + 16 * D_DIM,      &buf[4096 + ((wv_ * 2 + 1) * 2 + 0) * 512]);
        gload_lds16(s + 16 * D_DIM + 32, &buf[4096 + ((wv_ * 2 + 1) * 2 + 1) * 512]);
    };
    auto compute = [&](const _Float16* buf) {
        const _Float16* Af = buf + lane * 8;
        const _Float16* Bf = buf + 4096 + wv_ * 2048 + lane * 8;
        half8 af[4][2], bf[2][2];
        for (int mi = 0; mi < 4; ++mi)
            for (int kk = 0; kk < 2; ++kk)
                af[mi][kk] = *(const half8*)(Af + (mi * 2 + kk) * 512);
        for (int ni = 0; ni < 2; ++ni)
            for (int kk = 0; kk < 2; ++kk)
                bf[ni][kk] = *(const half8*)(Bf + (ni * 2 + kk) * 512);
        for (int kk = 0; kk < 2; ++kk)
            for (int mi = 0; mi < 4; ++mi)
                for (int ni = 0; ni < 2; ++ni)
                    acc[mi][ni] = __builtin_amdgcn_mfma_f32_16x16x32_f16(af[mi][kk], bf[ni][kk],
                                                                         acc[mi][ni], 0, 0, 0);
    };

#define LOADA(R0, R1, R2, R3, p)                           \
    R0 = *(const float4*)(xa + (p) * 64);                  \
    R1 = *(const float4*)(xa + (p) * 64 + 4);              \
    R2 = *(const float4*)(xa + (p) * 64 + 8);              \
    R3 = *(const float4*)(xa + (p) * 64 + 12);

    float4 aA0, aA1, aA2, aA3, aB0, aB1, aB2, aB3;
    LOADA(aA0, aA1, aA2, aA3, 0)
    LOADA(aB0, aB1, aB2, aB3, 1)
    stageB(smem, 0);

    for (int p = 0; p < 32; p += 2) {
        stageA(smem, aA0, aA1, aA2, aA3);
        __syncthreads();
        if (p + 2 < 32) { LOADA(aA0, aA1, aA2, aA3, p + 2) }
        stageB(smem + 12288, p + 1);
        compute(smem);
        stageA(smem + 12288, aB0, aB1, aB2, aB3);
        __syncthreads();
        if (p + 3 < 32) { LOADA(aB0, aB1, aB2, aB3, p + 3) }
        if (p + 2 < 32) stageB(smem, p + 2);
        compute(smem + 12288);
    }
#undef LOADA
    __syncthreads();

    float* sf = (float*)smem;  // [64][132] f32
    for (int mi = 0; mi < 4; ++mi)
        for (int ni = 0; ni < 2; ++ni)
            for (int r = 0; r < 4; ++r)
                sf[(mi * 16 + quad * 4 + r) * 132 + wv_ * 32 + ni * 16 + l15] =
                    acc[mi][ni][r];
    __syncthreads();
    const int row = tid >> 2, c0 = (tid & 3) * 32;
    float* dst = P + ((size_t)(ks * 3 + bx) * 8192 + M0 + row) * HD + c0;
    for (int j = 0; j < 8; ++j)
        *(float4*)(dst + j * 4) = *(const float4*)&sf[row * 132 + c0 + j * 4];
}

// ---------------- kernel 1b: combine K-split partials + RoPE (table) + V-transpose ----------------
__global__ __launch_bounds__(256) void combine_kernel(const float* __restrict__ P,
                                                      const float* __restrict__ tab,
                                                      _Float16* __restrict__ qw,
                                                      _Float16* __restrict__ kw,
                                                      _Float16* __restrict__ vt) {
    const int tid = threadIdx.x;
    const int M0 = blockIdx.x * 64;
    const int row = tid >> 2, c0 = (tid & 3) * 32;
    if (blockIdx.y == 0) {
        const float* Pq0 = P + ((size_t)0 * 8192 + M0 + row) * HD + c0;
        const float* Pq1 = P + ((size_t)3 * 8192 + M0 + row) * HD + c0;
        const float* Pk0 = P + ((size_t)1 * 8192 + M0 + row) * HD + c0;
        const float* Pk1 = P + ((size_t)4 * 8192 + M0 + row) * HD + c0;
        float qv[32], kv[32];
#pragma unroll
        for (int j = 0; j < 8; ++j) {
            float4 a = *(const float4*)(Pq0 + j * 4);
            float4 b = *(const float4*)(Pq1 + j * 4);
            float4 c = *(const float4*)(Pk0 + j * 4);
            float4 d = *(const float4*)(Pk1 + j * 4);
            qv[j * 4 + 0] = a.x + b.x; qv[j * 4 + 1] = a.y + b.y;
            qv[j * 4 + 2] = a.z + b.z; qv[j * 4 + 3] = a.w + b.w;
            kv[j * 4 + 0] = c.x + d.x; kv[j * 4 + 1] = c.y + d.y;
            kv[j * 4 + 2] = c.z + d.z; kv[j * 4 + 3] = c.w + d.w;
        }
        const int s = (M0 + row) & (S_LEN - 1);
        const float2* tb = (const float2*)tab + s * 64 + (c0 >> 1);
        half8 oq[4], ok[4];
#pragma unroll
        for (int jp = 0; jp < 16; ++jp) {
            const float2 cs = tb[jp];
            const float cn = cs.x, sn = cs.y;
            const float q0 = qv[2 * jp], q1 = qv[2 * jp + 1];
            const float k0 = kv[2 * jp], k1 = kv[2 * jp + 1];
            oq[jp >> 2][(2 * jp) & 7]     = (_Float16)(q0 * cn - q1 * sn);
            oq[jp >> 2][(2 * jp + 1) & 7] = (_Float16)(q1 * cn + q0 * sn);
            ok[jp >> 2][(2 * jp) & 7]     = (_Float16)(k0 * cn - k1 * sn);
            ok[jp >> 2][(2 * jp + 1) & 7] = (_Float16)(k1 * cn + k0 * sn);
        }
        _Float16* qdst = qw + (size_t)(M0 + row) * HD + c0;
        _Float16* kdst = kw + (size_t)(M0 + row) * HD + c0;
#pragma unroll
        for (int j = 0; j < 4; ++j) {
            *(half8*)(qdst + j * 8) = oq[j];
            *(half8*)(kdst + j * 8) = ok[j];
        }
    } else {
        __shared__ __align__(16) _Float16 sh[128][72];
        const float* Pv0 = P + ((size_t)2 * 8192 + M0 + row) * HD + c0;
        const float* Pv1 = P + ((size_t)5 * 8192 + M0 + row) * HD + c0;
#pragma unroll
        for (int j = 0; j < 8; ++j) {
            float4 a = *(const float4*)(Pv0 + j * 4);
            float4 b = *(const float4*)(Pv1 + j * 4);
            sh[c0 + j * 4 + 0][row] = (_Float16)(a.x + b.x);
            sh[c0 + j * 4 + 1][row] = (_Float16)(a.y + b.y);
            sh[c0 + j * 4 + 2][row] = (_Float16)(a.z + b.z);
            sh[c0 + j * 4 + 3][row] = (_Float16)(a.w + b.w);
        }
        __syncthreads();
        const int hd = tid >> 1, s0 = (tid & 1) * 32;
        _Float16* dst = vt + (size_t)(M0 >> 12) * HD * S_LEN + (size_t)hd * S_LEN +
                        (M0 & (S_LEN - 1)) + s0;
        for (int j = 0; j < 4; ++j)
            *(half8*)(dst + j * 8) = *(const half8*)&sh[hd][s0 + j * 8];
    }
}

// ---------------- attention core (R3-verified body; va loads hoisted to caller) ----------------
__device__ __forceinline__ void load_kf(const _Float16* __restrict__ kb, int kbase,
                                        int l15, int quad, half8* kf) {
    const _Float16* kr = kb + (size_t)(kbase + l15) * HD + quad * 8;
    for (int kk = 0; kk < 4; ++kk) {
        kf[kk]     = *(const half8*)(kr + kk * 32);
        kf[4 + kk] = *(const half8*)(kr + 16 * HD + kk * 32);
    }
}

__device__ __forceinline__ void load_vf(const _Float16* __restrict__ vtb, int kbase,
                                        int l15, int quad, half8* va) {
    const _Float16* vr = vtb + (size_t)l15 * S_LEN + kbase + quad * 8;
    for (int c = 0; c < 8; ++c)
        va[c] = *(const half8*)(vr + (size_t)c * 16 * S_LEN);
}

template<bool MASKED>
__device__ __forceinline__ void attn_sub(int kbase, int qg, int l15, int quad,
                                         const half8* kf, const half8* va,
                                         const half8* bq, f32x4* acc,
                                         float& mrun, float& lrun) {
    const float csc = 0.1275174348796053f;  // (1/sqrt(128)) * log2(e)
    f32x4 st0 = (f32x4){0.f, 0.f, 0.f, 0.f};
    f32x4 st1 = (f32x4){0.f, 0.f, 0.f, 0.f};
    for (int kk = 0; kk < 4; ++kk) {
        st0 = __builtin_amdgcn_mfma_f32_16x16x32_f16(kf[kk],     bq[kk], st0, 0, 0, 0);
        st1 = __builtin_amdgcn_mfma_f32_16x16x32_f16(kf[4 + kk], bq[kk], st1, 0, 0, 0);
    }
    float p0[4], p1[4];
    float mloc = -1e30f;
    for (int r = 0; r < 4; ++r) {
        float v0 = st0[r] * csc;
        float v1 = st1[r] * csc;
        if (MASKED) {
            const int key0 = kbase + quad * 4 + r;
            if (key0 > qg)      v0 = -1e30f;
            if (key0 + 16 > qg) v1 = -1e30f;
        }
        p0[r] = v0; p1[r] = v1;
        mloc = fmaxf(mloc, fmaxf(v0, v1));
    }
    mloc = fmaxf(mloc, __shfl_xor(mloc, 16));
    mloc = fmaxf(mloc, __shfl_xor(mloc, 32));
    const float mnew = fmaxf(mrun, mloc);
    const float alpha = exp2f(mrun - mnew);
    mrun = mnew;
    float ls = 0.f;
    for (int r = 0; r < 4; ++r) {
        p0[r] = exp2f(p0[r] - mnew);
        p1[r] = exp2f(p1[r] - mnew);
        ls += p0[r] + p1[r];
    }
    ls += __shfl_xor(ls, 16);
    ls += __shfl_xor(ls, 32);
    lrun = lrun * alpha + ls;
    for (int c = 0; c < 8; ++c)
        acc[c] *= alpha;
    int ph0 = __builtin_bit_cast(int, __builtin_amdgcn_cvt_pkrtz(p0[0], p0[1]));
    int ph1 = __builtin_bit_cast(int, __builtin_amdgcn_cvt_pkrtz(p0[2], p0[3]));
    int ph2 = __builtin_bit_cast(int, __builtin_amdgcn_cvt_pkrtz(p1[0], p1[1]));
    int ph3 = __builtin_bit_cast(int, __builtin_amdgcn_cvt_pkrtz(p1[2], p1[3]));
    const int s0 = (l15 + (((quad << 1)    ) & 3) * 16) * 4;
    const int s1 = (l15 + (((quad << 1) + 1) & 3) * 16) * 4;
    int a0 = __builtin_amdgcn_ds_bpermute(s0, ph0);
    int a1 = __builtin_amdgcn_ds_bpermute(s0, ph1);
    int a2 = __builtin_amdgcn_ds_bpermute(s1, ph0);
    int a3 = __builtin_amdgcn_ds_bpermute(s1, ph1);
    int b0 = __builtin_amdgcn_ds_bpermute(s0, ph2);
    int b1 = __builtin_amdgcn_ds_bpermute(s0, ph3);
    int b2 = __builtin_amdgcn_ds_bpermute(s1, ph2);
    int b3 = __builtin_amdgcn_ds_bpermute(s1, ph3);
    const bool lo = quad < 2;
    int4 pi = { lo ? a0 : b0, lo ? a1 : b1, lo ? a2 : b2, lo ? a3 : b3 };
    half8 pf = __builtin_bit_cast(half8, pi);
    for (int c = 0; c < 8; ++c)
        acc[c] = __builtin_amdgcn_mfma_f32_16x16x32_f16(va[c], pf, acc[c], 0, 0, 0);
}

// ---------------- kernel 3: attention, QBLK=32 (R17) ----------------
// 256 blocks = 2 batch x 128 32-row q-tiles; each wave owns a K-range slice and runs
// BOTH 16-row sub-tiles against shared K/V fragments -- per-output global-load issue
// and latency halve vs the 16-row structure (which plateaued ~190 TF across 3 nulls).
__global__ __launch_bounds__(256) void attn_kernel(const _Float16* __restrict__ q,
                                                   const _Float16* __restrict__ k,
                                                   const _Float16* __restrict__ vt,
                                                   float* __restrict__ out) {
    __shared__ __align__(16) float Osh[4][16][132];
    __shared__ float msh[4][16];
    __shared__ float lsh[4][16];
    const int tid = threadIdx.x;
    const int lane = tid & 63, wv_ = tid >> 6;
    const int l15 = lane & 15, quad = lane >> 4;
    const int bidx = blockIdx.x;
    const int b = bidx & 1;
    const int t = 127 - (bidx >> 1);  // longest q-tiles first
    const int qb = t * 32;

    const _Float16* qp = q + (size_t)(b * S_LEN + qb) * HD;
    half8 bq0[4], bq1[4];
    for (int kk = 0; kk < 4; ++kk) {
        bq0[kk] = *(const half8*)&qp[l15 * HD + kk * 32 + quad * 8];
        bq1[kk] = *(const half8*)&qp[(16 + l15) * HD + kk * 32 + quad * 8];
    }

    f32x4 acc0[8], acc1[8];
    for (int c = 0; c < 8; ++c) {
        acc0[c] = (f32x4){0.f, 0.f, 0.f, 0.f};
        acc1[c] = (f32x4){0.f, 0.f, 0.f, 0.f};
    }
    float m0 = -1e30f, l0 = 0.f, m1 = -1e30f, l1 = 0.f;

    const _Float16* kb = k + (size_t)b * S_LEN * HD;
    const _Float16* vtb = vt + (size_t)b * HD * S_LEN;

    // full 32-key tiles: i such that i*32+31 <= qb  ->  nfull = t; then one masked
    // tile at kbase = qb covering keys [qb, qb+31] for both sub-tiles.
    const int nfull = t;
    const int kend = qb;
    const bool hasm = ((nfull & 3) == wv_);
    const int kb0 = wv_ * 32;

    half8 kf[8], va[8];
    for (int kbase = kb0; kbase < kend; kbase += 128) {
        load_kf(kb, kbase, l15, quad, kf);
        load_vf(vtb, kbase, l15, quad, va);
        attn_sub<false>(kbase, qb + l15,      l15, quad, kf, va, bq0, acc0, m0, l0);
        attn_sub<false>(kbase, qb + 16 + l15, l15, quad, kf, va, bq1, acc1, m1, l1);
    }
    if (hasm) {
        load_kf(kb, kend, l15, quad, kf);
        load_vf(vtb, kend, l15, quad, va);
        attn_sub<true>(kend, qb + l15,      l15, quad, kf, va, bq0, acc0, m0, l0);
        attn_sub<true>(kend, qb + 16 + l15, l15, quad, kf, va, bq1, acc1, m1, l1);
    }

    // two-pass epilogue: verified Osh merge, reused for each 16-row sub-tile
    for (int s = 0; s < 2; ++s) {
        if (s) __syncthreads();  // prior merge reads complete before overwrite
        const f32x4* accs = s ? acc1 : acc0;
        for (int c = 0; c < 8; ++c)
            *(f32x4*)&Osh[wv_][l15][c * 16 + quad * 4] = accs[c];
        if (quad == 0) {
            msh[wv_][l15] = s ? m1 : m0;
            lsh[wv_][l15] = s ? l1 : l0;
        }
        __syncthreads();

        const int qr = tid >> 4, dg = (tid & 15) * 8;
        float w0 = msh[0][qr], w1 = msh[1][qr], w2 = msh[2][qr], w3 = msh[3][qr];
        float mm = fmaxf(fmaxf(w0, w1), fmaxf(w2, w3));
        float f0 = exp2f(w0 - mm), f1 = exp2f(w1 - mm);
        float f2 = exp2f(w2 - mm), f3 = exp2f(w3 - mm);
        float l = lsh[0][qr] * f0 + lsh[1][qr] * f1 + lsh[2][qr] * f2 + lsh[3][qr] * f3;
        f32x4 oa = (f32x4){0.f, 0.f, 0.f, 0.f}, ob = oa;
        oa += *(f32x4*)&Osh[0][qr][dg] * f0;  ob += *(f32x4*)&Osh[0][qr][dg + 4] * f0;
        oa += *(f32x4*)&Osh[1][qr][dg] * f1;  ob += *(f32x4*)&Osh[1][qr][dg + 4] * f1;
        oa += *(f32x4*)&Osh[2][qr][dg] * f2;  ob += *(f32x4*)&Osh[2][qr][dg + 4] * f2;
        oa += *(f32x4*)&Osh[3][qr][dg] * f3;  ob += *(f32x4*)&Osh[3][qr][dg + 4] * f3;
        const float inv = 1.0f / l;
        float* op = out + (size_t)(b * S_LEN + qb + s * 16 + qr) * HD + dg;
        *(float4*)op       = (float4){oa[0] * inv, oa[1] * inv, oa[2] * inv, oa[3] * inv};
        *(float4*)(op + 4) = (float4){ob[0] * inv, ob[1] * inv, ob[2] * inv, ob[3] * inv};
    }
}

extern "C" void kernel_launch(void* const* d_in, const int* in_sizes, int n_in,
                              void* d_out, int out_size, void* d_ws, size_t ws_size,
                              hipStream_t stream) {
    const float* x  = (const float*)d_in[0];
    const float* Wq = (const float*)d_in[1];
    const float* Wk = (const float*)d_in[2];
    const float* Wv = (const float*)d_in[3];
    float* out = (float*)d_out;
    char* ws = (char*)d_ws;
    _Float16* qw = (_Float16*)(ws);
    _Float16* kw = (_Float16*)(ws + (2u << 20));
    _Float16* vt = (_Float16*)(ws + (4u << 20));
    _Float16* wh = (_Float16*)(ws + (6u << 20));            // 3 MiB
    float* P   = (float*)(ws + (9u << 20));                 // 24 MiB
    float* tab = (float*)(ws + (33u << 20));                // 2 MiB

    setup_kernel<<<dim3(1792), dim3(256), 0, stream>>>(Wq, Wk, Wv, wh, tab);
    proj64_kernel<<<dim3(768), dim3(256), 0, stream>>>(x, wh, P);
    combine_kernel<<<dim3(128, 2), dim3(256), 0, stream>>>(P, tab, qw, kw, vt);
    attn_kernel<<<dim3(256), dim3(256), 0, stream>>>(qw, kw, vt, out);
}